// Round 11
// baseline (5575.117 us; speedup 1.0000x reference)
//
#include <hip/hip_runtime.h>
#include <cstdint>
#include <cstddef>

#define EPSV 1e-5f

using f32x4  = __attribute__((ext_vector_type(4))) float;
using bf16x8 = __attribute__((ext_vector_type(8))) short;

// RNE pack of two f32 into two bf16 (lo -> low16, hi -> high16)
static __device__ __forceinline__ unsigned pk2(float lo, float hi) {
    unsigned a = __builtin_bit_cast(unsigned, lo);
    unsigned b = __builtin_bit_cast(unsigned, hi);
    a = (a + 0x7FFFu + ((a >> 16) & 1u)) >> 16;
    b = (b + 0x7FFFu + ((b >> 16) & 1u)) & 0xFFFF0000u;
    return a | b;
}
static __device__ __forceinline__ unsigned short bf16of(float v) {
    return (unsigned short)(pk2(v, 0.f) & 0xFFFFu);
}
static __device__ __forceinline__ void unpk2(unsigned u, float& lo, float& hi) {
    lo = __builtin_bit_cast(float, u << 16);
    hi = __builtin_bit_cast(float, u & 0xFFFF0000u);
}

// ---------------------------------------------------------------------------
__global__ __launch_bounds__(256) void prep_params(
    const float* __restrict__ rwb, const float* __restrict__ rg,
    const float* __restrict__ rb,  const float* __restrict__ rm,
    const float* __restrict__ rv,
    const float* __restrict__ ewb, const float* __restrict__ eg,
    const float* __restrict__ eb,  const float* __restrict__ em,
    const float* __restrict__ ev,
    const float* __restrict__ bg,  const float* __restrict__ bb,
    const float* __restrict__ bm,  const float* __restrict__ bv,
    float* __restrict__ prm)
{
    int t = threadIdx.x;
    if (t < 128) {
        float sc = rg[t] * rsqrtf(rv[t] + EPSV);
        prm[t]       = sc;
        prm[128 + t] = rb[t] - rm[t] * sc + rwb[t] * sc;
        float bsc = bg[t] * rsqrtf(bv[t] + EPSV);
        prm[768 + t] = bsc;
        prm[896 + t] = bb[t] - bm[t] * bsc;
    }
    {
        float sc = eg[t] * rsqrtf(ev[t] + EPSV);
        prm[256 + t] = sc;
        prm[512 + t] = eb[t] - em[t] * sc + ewb[t] * sc;
    }
}

// ---------------------------------------------------------------------------
// Reduct GEMM (round-9 verified, unchanged): x f32 [n][256][1600] ->
// hT bf16 [n][1600][128]. BK=64, 32 KB LDS, vectorized I/O.
// ---------------------------------------------------------------------------
__global__ __launch_bounds__(256) void gemm_reduct(
    const float* __restrict__ Bsrc,
    const float* __restrict__ Wt,
    const float* __restrict__ scale,
    const float* __restrict__ shift,
    unsigned short* __restrict__ OutP,
    int Cin, int O, int P)
{
    const int n    = blockIdx.z;
    const int p0   = blockIdx.x * 64;
    const int o0   = blockIdx.y * 128;
    const int tid  = threadIdx.x;
    const int lane = tid & 63;
    const int wid  = tid >> 6;
    const int wm   = wid >> 1, wn = wid & 1;
    const int rl   = lane & 15;

    __shared__ __align__(16) char smem[32768];
    short* sA = (short*)smem;                       // 16 KB [128][64] swz

    f32x4 acc[4][2];
    #pragma unroll
    for (int i = 0; i < 4; ++i)
        #pragma unroll
        for (int j = 0; j < 2; ++j) acc[i][j] = (f32x4)0.f;

    for (int kc = 0; kc < Cin; kc += 64) {
        if (kc) __syncthreads();

        #pragma unroll
        for (int it = 0; it < 4; ++it) {
            int idx = tid + it * 256;
            int row = idx >> 3, k8 = (idx & 7) << 3;
            const float* wp = Wt + (size_t)(o0 + row) * Cin + kc + k8;
            float4 u = *(const float4*)wp;
            float4 v = *(const float4*)(wp + 4);
            uint4 w = make_uint4(pk2(u.x, u.y), pk2(u.z, u.w),
                                 pk2(v.x, v.y), pk2(v.z, v.w));
            *(uint4*)(&sA[(row << 6) + (k8 ^ ((row & 7) << 3))]) = w;
        }
        {
            float* sBf = (float*)(smem + 16384);    // [64 k][64 p] rotated
            #pragma unroll
            for (int it = 0; it < 4; ++it) {
                int idx = tid + it * 256;
                int k = idx >> 4, p4 = (idx & 15) << 2;
                float4 u = *(const float4*)((const float*)Bsrc
                    + (size_t)n * Cin * P + (size_t)(kc + k) * P + p0 + p4);
                *(float4*)(&sBf[(k << 6) + ((p4 + (((k >> 3) & 7) << 3)) & 63)]) = u;
            }
        }
        __syncthreads();

        #pragma unroll
        for (int ks = 0; ks < 2; ++ks) {
            const int k0 = ks * 32 + (lane >> 4) * 8;
            bf16x8 af[4], bfr[2];
            #pragma unroll
            for (int i = 0; i < 4; ++i) {
                int row = wm * 64 + i * 16 + rl;
                af[i] = *(const bf16x8*)(&sA[(row << 6) + (k0 ^ ((rl & 7) << 3))]);
            }
            {
                const float* sBf = (const float*)(smem + 16384);
                #pragma unroll
                for (int j = 0; j < 2; ++j) {
                    int p = wn * 32 + j * 16 + rl;
                    int base = (p + ((k0 >> 3) << 3)) & 63;
                    float f[8];
                    #pragma unroll
                    for (int q = 0; q < 8; ++q)
                        f[q] = sBf[((k0 + q) << 6) + base];
                    uint4 u = make_uint4(pk2(f[0], f[1]), pk2(f[2], f[3]),
                                         pk2(f[4], f[5]), pk2(f[6], f[7]));
                    bfr[j] = __builtin_bit_cast(bf16x8, u);
                }
            }
            #pragma unroll
            for (int i = 0; i < 4; ++i)
                #pragma unroll
                for (int j = 0; j < 2; ++j)
                    acc[i][j] = __builtin_amdgcn_mfma_f32_16x16x32_bf16(
                        af[i], bfr[j], acc[i][j], 0, 0, 0);
        }
    }

    // transposed bf16 epilogue -> [p][O] (verified)
    __syncthreads();
    unsigned short* eL = (unsigned short*)smem;   // [64 p][128 o]
    #pragma unroll
    for (int i = 0; i < 4; ++i) {
        #pragma unroll
        for (int r = 0; r < 4; ++r) {
            int ol = wm * 64 + i * 16 + (lane >> 4) * 4 + r;
            int o  = o0 + ol;
            float sc = scale[o], sh = shift[o];
            #pragma unroll
            for (int j = 0; j < 2; ++j) {
                int p = wn * 32 + j * 16 + rl;
                float v = fmaxf(fmaf(acc[i][j][r], sc, sh), 0.f);
                eL[p * 128 + (ol ^ ((p & 15) << 3))] = bf16of(v);
            }
        }
    }
    __syncthreads();
    #pragma unroll
    for (int it = 0; it < 4; ++it) {
        int idx = tid + it * 256;
        int p = idx >> 4, m = idx & 15;
        uint4 u = *(const uint4*)(&eL[p * 128 + ((m ^ (p & 15)) << 3)]);
        *(uint4*)(OutP + ((size_t)n * P + p0 + p) * O + (m << 3)) = u;
    }
}

// ---------------------------------------------------------------------------
// Fused res2net chain + expand conv. One block per (n, 200-p tile).
// gcn state/outputs stay in LDS; expand MFMA reads outb directly; output
// written once (f32, float4) with residual + BN + ReLU.
// ---------------------------------------------------------------------------
__global__ __launch_bounds__(256) void gcn_expand(
    const unsigned short* __restrict__ hT,   // [64][1600][128] bf16
    const float* __restrict__ gw,            // [4][96][32]
    const float* __restrict__ gb,            // [4][96]
    const float* __restrict__ Aadj,          // [3][25][25]
    const float* __restrict__ PA,            // [4][3][25][25]
    const float* __restrict__ bsc4,          // [4][32]
    const float* __restrict__ bsh4,          // [4][32]
    const float* __restrict__ ew,            // [256][128]
    const float* __restrict__ escale,        // [256]
    const float* __restrict__ eshift,        // [256]
    const float* __restrict__ xres,          // [64][256][1600]
    float* __restrict__ outg)                // [64][256][1600]
{
    const int n   = blockIdx.y;
    const int tt  = blockIdx.x;
    const int tid = threadIdx.x;
    const int lane = tid & 63;
    const int wid  = tid >> 6;
    const int rl   = lane & 15;
    const int c  = tid & 31;
    const int tl = tid >> 5;

    // outb[p][cv] bf16, cv-granules XOR-swizzled by (p&15)
    __shared__ __align__(16) unsigned short outb[208 * 128];  // 53,248 B
    __shared__ __align__(16) char r2[26624];
    unsigned short* spb = (unsigned short*)r2;   // [200][32] bf16  12,800 B
    float* MmA = (float*)(r2 + 12800);           // [75][28] f32     8,400 B
    short* sAe = (short*)r2;                     // expand A  8,192 B (alias)
    float* eT  = (float*)(r2 + 8192);            // [128][36] f32   18,432 B

    const size_t rowbase = (size_t)n * 1600 + (size_t)tt * 200;

    // ---- init: spb = hT chunk 0 (bf16 copy), Mm step 0 ----
    {
        const unsigned short* hrow = hT + rowbase * 128;
        for (int idx = tid; idx < 800; idx += 256) {
            int p = idx >> 2, c8 = (idx & 3) << 3;
            *(uint4*)(&spb[p * 32 + c8]) =
                *(const uint4*)(hrow + (size_t)p * 128 + c8);
        }
        for (int idx = tid; idx < 1875; idx += 256)
            MmA[(idx / 25) * 28 + (idx % 25)] = Aadj[idx] + PA[idx];
    }
    __syncthreads();

    // ================= gcn chain =================
    for (int step = 0; step < 4; ++step) {
        // ---- conv 32->96: weights from global (L1/L2), spb b128+unpack ----
        float g[3][25];
        {
            const float* gbp = gb + step * 96;
            float b0 = gbp[c], b1 = gbp[32 + c], b2 = gbp[64 + c];
            #pragma unroll
            for (int v = 0; v < 25; ++v) { g[0][v] = b0; g[1][v] = b1; g[2][v] = b2; }
        }
        const float* gwp = gw + step * 96 * 32;
        #pragma unroll
        for (int kb = 0; kb < 32; kb += 8) {
            float w0[8], w1[8], w2[8];
            *(float4*)&w0[0] = *(const float4*)(gwp + c * 32 + kb);
            *(float4*)&w0[4] = *(const float4*)(gwp + c * 32 + kb + 4);
            *(float4*)&w1[0] = *(const float4*)(gwp + (32 + c) * 32 + kb);
            *(float4*)&w1[4] = *(const float4*)(gwp + (32 + c) * 32 + kb + 4);
            *(float4*)&w2[0] = *(const float4*)(gwp + (64 + c) * 32 + kb);
            *(float4*)&w2[4] = *(const float4*)(gwp + (64 + c) * 32 + kb + 4);
            #pragma unroll
            for (int v = 0; v < 25; ++v) {
                uint4 u = *(const uint4*)(&spb[(tl * 25 + v) * 32 + kb]);
                float f[8];
                unpk2(u.x, f[0], f[1]); unpk2(u.y, f[2], f[3]);
                unpk2(u.z, f[4], f[5]); unpk2(u.w, f[6], f[7]);
                #pragma unroll
                for (int q = 0; q < 8; ++q) {
                    g[0][v] = fmaf(w0[q], f[q], g[0][v]);
                    g[1][v] = fmaf(w1[q], f[q], g[1][v]);
                    g[2][v] = fmaf(w2[q], f[q], g[2][v]);
                }
            }
        }

        // ---- adjacency mix ----
        float ov[25];
        #pragma unroll
        for (int w = 0; w < 25; ++w) ov[w] = 0.f;
        #pragma unroll
        for (int k = 0; k < 3; ++k)
            #pragma unroll
            for (int v = 0; v < 25; ++v) {
                float gv = g[k][v];
                const float* mrow = MmA + (k * 25 + v) * 28;
                #pragma unroll
                for (int w = 0; w < 25; ++w)
                    ov[w] = fmaf(gv, mrow[w], ov[w]);
            }

        // ---- BN + ReLU ----
        {
            float sc = bsc4[step * 32 + c], sh = bsh4[step * 32 + c];
            #pragma unroll
            for (int w = 0; w < 25; ++w)
                ov[w] = fmaxf(fmaf(ov[w], sc, sh), 0.f);
        }

        __syncthreads();   // conv/mix reads of spb & MmA complete

        if (step < 3) {
            // spb <- hT chunk step+1 ; Mm <- step+1
            const unsigned short* hrow = hT + rowbase * 128 + (step + 1) * 32;
            for (int idx = tid; idx < 800; idx += 256) {
                int p = idx >> 2, c8 = (idx & 3) << 3;
                *(uint4*)(&spb[p * 32 + c8]) =
                    *(const uint4*)(hrow + (size_t)p * 128 + c8);
            }
            const float* pap = PA + (step + 1) * 1875;
            for (int idx = tid; idx < 1875; idx += 256)
                MmA[(idx / 25) * 28 + (idx % 25)] = Aadj[idx] + pap[idx];
        }
        __syncthreads();   // spb holds h, Mm ready

        // ---- write outb chunk (swizzled) + spb += out ----
        {
            const int cv = step * 32 + c;
            #pragma unroll
            for (int w = 0; w < 25; ++w) {
                int p = tl * 25 + w;
                outb[p * 128 + ((((cv >> 3) ^ (p & 15)) << 3) | (cv & 7))] =
                    bf16of(ov[w]);
                if (step < 3) {
                    int a = p * 32 + c;
                    float hv = __builtin_bit_cast(float, (unsigned)spb[a] << 16);
                    spb[a] = bf16of(hv + ov[w]);
                }
            }
        }
        __syncthreads();   // outb/spb committed
    }

    // ================= expand: out = ReLU(BN(ew @ outs) + x) =================
    for (int half = 0; half < 2; ++half) {
        f32x4 acc[2][13];
        #pragma unroll
        for (int m = 0; m < 2; ++m)
            #pragma unroll
            for (int j2 = 0; j2 < 13; ++j2) acc[m][j2] = (f32x4)0.f;

        for (int kc = 0; kc < 4; ++kc) {
            __syncthreads();   // prior sAe readers (or gcn phase) done
            {
                int row = tid >> 1, kq = (tid & 1) << 4;
                const float* wr = ew + (size_t)(half * 128 + row) * 128
                                + kc * 32 + kq;
                float4 a0 = *(const float4*)wr;
                float4 a1 = *(const float4*)(wr + 4);
                float4 a2 = *(const float4*)(wr + 8);
                float4 a3 = *(const float4*)(wr + 12);
                uint4 u0 = make_uint4(pk2(a0.x, a0.y), pk2(a0.z, a0.w),
                                      pk2(a1.x, a1.y), pk2(a1.z, a1.w));
                uint4 u1 = make_uint4(pk2(a2.x, a2.y), pk2(a2.z, a2.w),
                                      pk2(a3.x, a3.y), pk2(a3.z, a3.w));
                *(uint4*)(&sAe[row * 32 + (kq ^ ((row & 3) << 3))]) = u0;
                *(uint4*)(&sAe[row * 32 + ((kq + 8) ^ ((row & 3) << 3))]) = u1;
            }
            __syncthreads();

            const int k0 = (lane >> 4) << 3;
            bf16x8 af[2];
            #pragma unroll
            for (int m = 0; m < 2; ++m) {
                int rowA = (wid * 2 + m) * 16 + rl;
                af[m] = *(const bf16x8*)(&sAe[rowA * 32 + (k0 ^ ((rl & 3) << 3))]);
            }
            const int gk = kc * 4 + (lane >> 4);
            #pragma unroll
            for (int j2 = 0; j2 < 13; ++j2) {
                int p = j2 * 16 + rl;
                bf16x8 bfv = *(const bf16x8*)(
                    &outb[p * 128 + ((gk ^ (p & 15)) << 3)]);
                #pragma unroll
                for (int m = 0; m < 2; ++m)
                    acc[m][j2] = __builtin_amdgcn_mfma_f32_16x16x32_bf16(
                        af[m], bfv, acc[m][j2], 0, 0, 0);
            }
        }

        // epilogue: per 32-p subtile through eT, float4 resid + store
        #pragma unroll
        for (int st = 0; st < 7; ++st) {
            __syncthreads();   // prior eT readers done
            #pragma unroll
            for (int m = 0; m < 2; ++m) {
                #pragma unroll
                for (int dj = 0; dj < 2; ++dj) {
                    int nj = st * 2 + dj;
                    if (nj < 13) {
                        #pragma unroll
                        for (int r = 0; r < 4; ++r) {
                            int ol = (wid * 2 + m) * 16 + ((lane >> 4) << 2) + r;
                            int o  = half * 128 + ol;
                            eT[ol * 36 + dj * 16 + rl] =
                                fmaf(acc[m][nj][r], escale[o], eshift[o]);
                        }
                    }
                }
            }
            __syncthreads();
            #pragma unroll
            for (int it = 0; it < 4; ++it) {
                int idx = tid + it * 256;
                int ol = idx >> 3, c4 = (idx & 7) << 2;
                int pl = st * 32 + c4;
                if (pl < 200) {
                    float4 v = *(const float4*)(&eT[ol * 36 + c4]);
                    size_t base = ((size_t)(n * 256 + half * 128 + ol)) * 1600
                                + (size_t)tt * 200 + pl;
                    float4 rx = *(const float4*)(xres + base);
                    v.x = fmaxf(v.x + rx.x, 0.f);
                    v.y = fmaxf(v.y + rx.y, 0.f);
                    v.z = fmaxf(v.z + rx.z, 0.f);
                    v.w = fmaxf(v.w + rx.w, 0.f);
                    *(float4*)(outg + base) = v;
                }
            }
        }
    }
}

// ---------------------------------------------------------------------------
extern "C" void kernel_launch(void* const* d_in, const int* in_sizes, int n_in,
                              void* d_out, int out_size, void* d_ws, size_t ws_size,
                              hipStream_t stream)
{
    const float* x   = (const float*)d_in[0];
    const float* A   = (const float*)d_in[1];
    const float* rw  = (const float*)d_in[2];
    const float* rwb = (const float*)d_in[3];
    const float* rg  = (const float*)d_in[4];
    const float* rb  = (const float*)d_in[5];
    const float* rm  = (const float*)d_in[6];
    const float* rv  = (const float*)d_in[7];
    const float* gw  = (const float*)d_in[8];
    const float* gb  = (const float*)d_in[9];
    const float* PA  = (const float*)d_in[10];
    const float* bg  = (const float*)d_in[11];
    const float* bb  = (const float*)d_in[12];
    const float* bm  = (const float*)d_in[13];
    const float* bv  = (const float*)d_in[14];
    const float* ew  = (const float*)d_in[15];
    const float* ewb = (const float*)d_in[16];
    const float* eg  = (const float*)d_in[17];
    const float* eb  = (const float*)d_in[18];
    const float* em  = (const float*)d_in[19];
    const float* ev  = (const float*)d_in[20];

    char* wsb = (char*)d_ws;
    unsigned short* hT  = (unsigned short*)wsb;           // 26,214,400 B
    float*          prm = (float*)(wsb + 26214400);       // 4 KB

    prep_params<<<1, 256, 0, stream>>>(rwb, rg, rb, rm, rv,
                                       ewb, eg, eb, em, ev,
                                       bg, bb, bm, bv, prm);

    // reduct: x -> hT bf16 [n][1600][128]
    gemm_reduct<<<dim3(25, 1, 64), 256, 0, stream>>>(
        x, rw, prm, prm + 128, hT, 256, 128, 1600);

    // fused res2net chain + expand (+x residual) -> d_out
    gcn_expand<<<dim3(8, 64), 256, 0, stream>>>(
        hT, gw, gb, A, PA, prm + 768, prm + 896,
        ew, prm + 256, prm + 512, x, (float*)d_out);
}

// Round 12
// 5493.467 us; speedup vs baseline: 1.0149x; 1.0149x over previous
//
#include <hip/hip_runtime.h>
#include <cstdint>
#include <cstddef>

#define EPSV 1e-5f

using f32x4  = __attribute__((ext_vector_type(4))) float;
using bf16x8 = __attribute__((ext_vector_type(8))) short;

// RNE pack of two f32 into two bf16 (lo -> low16, hi -> high16)
static __device__ __forceinline__ unsigned pk2(float lo, float hi) {
    unsigned a = __builtin_bit_cast(unsigned, lo);
    unsigned b = __builtin_bit_cast(unsigned, hi);
    a = (a + 0x7FFFu + ((a >> 16) & 1u)) >> 16;
    b = (b + 0x7FFFu + ((b >> 16) & 1u)) & 0xFFFF0000u;
    return a | b;
}
static __device__ __forceinline__ unsigned short bf16of(float v) {
    return (unsigned short)(pk2(v, 0.f) & 0xFFFFu);
}
static __device__ __forceinline__ void unpk2(unsigned u, float& lo, float& hi) {
    lo = __builtin_bit_cast(float, u << 16);
    hi = __builtin_bit_cast(float, u & 0xFFFF0000u);
}
// pack 8 k-consecutive f32 (two float4) into bf16x8
static __device__ __forceinline__ bf16x8 pk8(float4 lo, float4 hi) {
    uint4 u = make_uint4(pk2(lo.x, lo.y), pk2(lo.z, lo.w),
                         pk2(hi.x, hi.y), pk2(hi.z, hi.w));
    return __builtin_bit_cast(bf16x8, u);
}

// ---------------------------------------------------------------------------
__global__ __launch_bounds__(256) void prep_params(
    const float* __restrict__ rwb, const float* __restrict__ rg,
    const float* __restrict__ rb,  const float* __restrict__ rm,
    const float* __restrict__ rv,
    const float* __restrict__ ewb, const float* __restrict__ eg,
    const float* __restrict__ eb,  const float* __restrict__ em,
    const float* __restrict__ ev,
    const float* __restrict__ bg,  const float* __restrict__ bb,
    const float* __restrict__ bm,  const float* __restrict__ bv,
    float* __restrict__ prm)
{
    int t = threadIdx.x;
    if (t < 128) {
        float sc = rg[t] * rsqrtf(rv[t] + EPSV);
        prm[t]       = sc;
        prm[128 + t] = rb[t] - rm[t] * sc + rwb[t] * sc;
        float bsc = bg[t] * rsqrtf(bv[t] + EPSV);
        prm[768 + t] = bsc;
        prm[896 + t] = bb[t] - bm[t] * bsc;
    }
    {
        float sc = eg[t] * rsqrtf(ev[t] + EPSV);
        prm[256 + t] = sc;
        prm[512 + t] = eb[t] - em[t] * sc + ewb[t] * sc;
    }
}

// ---------------------------------------------------------------------------
// Reduct GEMM (round-9 verified, unchanged): x f32 [n][256][1600] ->
// hT bf16 [n][1600][128]. BK=64, 32 KB LDS, vectorized I/O.
// ---------------------------------------------------------------------------
__global__ __launch_bounds__(256) void gemm_reduct(
    const float* __restrict__ Bsrc,
    const float* __restrict__ Wt,
    const float* __restrict__ scale,
    const float* __restrict__ shift,
    unsigned short* __restrict__ OutP,
    int Cin, int O, int P)
{
    const int n    = blockIdx.z;
    const int p0   = blockIdx.x * 64;
    const int o0   = blockIdx.y * 128;
    const int tid  = threadIdx.x;
    const int lane = tid & 63;
    const int wid  = tid >> 6;
    const int wm   = wid >> 1, wn = wid & 1;
    const int rl   = lane & 15;

    __shared__ __align__(16) char smem[32768];
    short* sA = (short*)smem;                       // 16 KB [128][64] swz

    f32x4 acc[4][2];
    #pragma unroll
    for (int i = 0; i < 4; ++i)
        #pragma unroll
        for (int j = 0; j < 2; ++j) acc[i][j] = (f32x4)0.f;

    for (int kc = 0; kc < Cin; kc += 64) {
        if (kc) __syncthreads();

        #pragma unroll
        for (int it = 0; it < 4; ++it) {
            int idx = tid + it * 256;
            int row = idx >> 3, k8 = (idx & 7) << 3;
            const float* wp = Wt + (size_t)(o0 + row) * Cin + kc + k8;
            float4 u = *(const float4*)wp;
            float4 v = *(const float4*)(wp + 4);
            uint4 w = make_uint4(pk2(u.x, u.y), pk2(u.z, u.w),
                                 pk2(v.x, v.y), pk2(v.z, v.w));
            *(uint4*)(&sA[(row << 6) + (k8 ^ ((row & 7) << 3))]) = w;
        }
        {
            float* sBf = (float*)(smem + 16384);    // [64 k][64 p] rotated
            #pragma unroll
            for (int it = 0; it < 4; ++it) {
                int idx = tid + it * 256;
                int k = idx >> 4, p4 = (idx & 15) << 2;
                float4 u = *(const float4*)((const float*)Bsrc
                    + (size_t)n * Cin * P + (size_t)(kc + k) * P + p0 + p4);
                *(float4*)(&sBf[(k << 6) + ((p4 + (((k >> 3) & 7) << 3)) & 63)]) = u;
            }
        }
        __syncthreads();

        #pragma unroll
        for (int ks = 0; ks < 2; ++ks) {
            const int k0 = ks * 32 + (lane >> 4) * 8;
            bf16x8 af[4], bfr[2];
            #pragma unroll
            for (int i = 0; i < 4; ++i) {
                int row = wm * 64 + i * 16 + rl;
                af[i] = *(const bf16x8*)(&sA[(row << 6) + (k0 ^ ((rl & 7) << 3))]);
            }
            {
                const float* sBf = (const float*)(smem + 16384);
                #pragma unroll
                for (int j = 0; j < 2; ++j) {
                    int p = wn * 32 + j * 16 + rl;
                    int base = (p + ((k0 >> 3) << 3)) & 63;
                    float f[8];
                    #pragma unroll
                    for (int q = 0; q < 8; ++q)
                        f[q] = sBf[((k0 + q) << 6) + base];
                    uint4 u = make_uint4(pk2(f[0], f[1]), pk2(f[2], f[3]),
                                         pk2(f[4], f[5]), pk2(f[6], f[7]));
                    bfr[j] = __builtin_bit_cast(bf16x8, u);
                }
            }
            #pragma unroll
            for (int i = 0; i < 4; ++i)
                #pragma unroll
                for (int j = 0; j < 2; ++j)
                    acc[i][j] = __builtin_amdgcn_mfma_f32_16x16x32_bf16(
                        af[i], bfr[j], acc[i][j], 0, 0, 0);
        }
    }

    // transposed bf16 epilogue -> [p][O] (verified)
    __syncthreads();
    unsigned short* eL = (unsigned short*)smem;   // [64 p][128 o]
    #pragma unroll
    for (int i = 0; i < 4; ++i) {
        #pragma unroll
        for (int r = 0; r < 4; ++r) {
            int ol = wm * 64 + i * 16 + (lane >> 4) * 4 + r;
            int o  = o0 + ol;
            float sc = scale[o], sh = shift[o];
            #pragma unroll
            for (int j = 0; j < 2; ++j) {
                int p = wn * 32 + j * 16 + rl;
                float v = fmaxf(fmaf(acc[i][j][r], sc, sh), 0.f);
                eL[p * 128 + (ol ^ ((p & 15) << 3))] = bf16of(v);
            }
        }
    }
    __syncthreads();
    #pragma unroll
    for (int it = 0; it < 4; ++it) {
        int idx = tid + it * 256;
        int p = idx >> 4, m = idx & 15;
        uint4 u = *(const uint4*)(&eL[p * 128 + ((m ^ (p & 15)) << 3)]);
        *(uint4*)(OutP + ((size_t)n * P + p0 + p) * O + (m << 3)) = u;
    }
}

// ---------------------------------------------------------------------------
// Fused res2net chain + expand conv. One block per (n, 200-p tile).
// gcn outputs stay in LDS (outb, swizzled); expand runs o-tile-at-a-time with
// all 4 waves splitting the p dimension -> acc is only 16 VGPRs/thread.
// ---------------------------------------------------------------------------
__global__ __launch_bounds__(256) void gcn_expand(
    const unsigned short* __restrict__ hT,   // [64][1600][128] bf16
    const float* __restrict__ gw,            // [4][96][32]
    const float* __restrict__ gb,            // [4][96]
    const float* __restrict__ Aadj,          // [3][25][25]
    const float* __restrict__ PA,            // [4][3][25][25]
    const float* __restrict__ bsc4,          // [4][32]
    const float* __restrict__ bsh4,          // [4][32]
    const float* __restrict__ ew,            // [256][128]
    const float* __restrict__ escale,        // [256]
    const float* __restrict__ eshift,        // [256]
    const float* __restrict__ xres,          // [64][256][1600]
    float* __restrict__ outg)                // [64][256][1600]
{
    const int n   = blockIdx.y;
    const int tt  = blockIdx.x;
    const int tid = threadIdx.x;
    const int lane = tid & 63;
    const int wid  = tid >> 6;
    const int rl   = lane & 15;
    const int g    = lane >> 4;
    const int c  = tid & 31;
    const int tl = tid >> 5;

    // outb[p][cv] bf16, cv-granules XOR-swizzled by (p&15)
    __shared__ __align__(16) unsigned short outb[208 * 128];  // 53,248 B
    __shared__ __align__(16) char r2[26624];
    unsigned short* spb = (unsigned short*)r2;   // [200][32] bf16  12,800 B
    float* MmA = (float*)(r2 + 12800);           // [75][28] f32     8,400 B
    float* eT  = (float*)r2;                     // [16][212] f32   13,568 B (alias)

    const size_t rowbase = (size_t)n * 1600 + (size_t)tt * 200;

    // ---- init: spb = hT chunk 0 (bf16 copy), Mm step 0 ----
    {
        const unsigned short* hrow = hT + rowbase * 128;
        for (int idx = tid; idx < 800; idx += 256) {
            int p = idx >> 2, c8 = (idx & 3) << 3;
            *(uint4*)(&spb[p * 32 + c8]) =
                *(const uint4*)(hrow + (size_t)p * 128 + c8);
        }
        for (int idx = tid; idx < 1875; idx += 256)
            MmA[(idx / 25) * 28 + (idx % 25)] = Aadj[idx] + PA[idx];
    }
    __syncthreads();

    // ================= gcn chain (round-11 verified) =================
    for (int step = 0; step < 4; ++step) {
        float gr[3][25];
        {
            const float* gbp = gb + step * 96;
            float b0 = gbp[c], b1 = gbp[32 + c], b2 = gbp[64 + c];
            #pragma unroll
            for (int v = 0; v < 25; ++v) { gr[0][v] = b0; gr[1][v] = b1; gr[2][v] = b2; }
        }
        const float* gwp = gw + step * 96 * 32;
        #pragma unroll
        for (int kb = 0; kb < 32; kb += 8) {
            float w0[8], w1[8], w2[8];
            *(float4*)&w0[0] = *(const float4*)(gwp + c * 32 + kb);
            *(float4*)&w0[4] = *(const float4*)(gwp + c * 32 + kb + 4);
            *(float4*)&w1[0] = *(const float4*)(gwp + (32 + c) * 32 + kb);
            *(float4*)&w1[4] = *(const float4*)(gwp + (32 + c) * 32 + kb + 4);
            *(float4*)&w2[0] = *(const float4*)(gwp + (64 + c) * 32 + kb);
            *(float4*)&w2[4] = *(const float4*)(gwp + (64 + c) * 32 + kb + 4);
            #pragma unroll
            for (int v = 0; v < 25; ++v) {
                uint4 u = *(const uint4*)(&spb[(tl * 25 + v) * 32 + kb]);
                float f[8];
                unpk2(u.x, f[0], f[1]); unpk2(u.y, f[2], f[3]);
                unpk2(u.z, f[4], f[5]); unpk2(u.w, f[6], f[7]);
                #pragma unroll
                for (int q = 0; q < 8; ++q) {
                    gr[0][v] = fmaf(w0[q], f[q], gr[0][v]);
                    gr[1][v] = fmaf(w1[q], f[q], gr[1][v]);
                    gr[2][v] = fmaf(w2[q], f[q], gr[2][v]);
                }
            }
        }

        float ov[25];
        #pragma unroll
        for (int w = 0; w < 25; ++w) ov[w] = 0.f;
        #pragma unroll
        for (int k = 0; k < 3; ++k)
            #pragma unroll
            for (int v = 0; v < 25; ++v) {
                float gv = gr[k][v];
                const float* mrow = MmA + (k * 25 + v) * 28;
                #pragma unroll
                for (int w = 0; w < 25; ++w)
                    ov[w] = fmaf(gv, mrow[w], ov[w]);
            }

        {
            float sc = bsc4[step * 32 + c], sh = bsh4[step * 32 + c];
            #pragma unroll
            for (int w = 0; w < 25; ++w)
                ov[w] = fmaxf(fmaf(ov[w], sc, sh), 0.f);
        }

        __syncthreads();   // conv/mix reads of spb & MmA complete

        if (step < 3) {
            const unsigned short* hrow = hT + rowbase * 128 + (step + 1) * 32;
            for (int idx = tid; idx < 800; idx += 256) {
                int p = idx >> 2, c8 = (idx & 3) << 3;
                *(uint4*)(&spb[p * 32 + c8]) =
                    *(const uint4*)(hrow + (size_t)p * 128 + c8);
            }
            const float* pap = PA + (step + 1) * 1875;
            for (int idx = tid; idx < 1875; idx += 256)
                MmA[(idx / 25) * 28 + (idx % 25)] = Aadj[idx] + pap[idx];
        }
        __syncthreads();   // spb holds h_{step+1}, Mm ready

        {
            const int cv = step * 32 + c;
            #pragma unroll
            for (int w = 0; w < 25; ++w) {
                int p = tl * 25 + w;
                outb[p * 128 + ((((cv >> 3) ^ (p & 15)) << 3) | (cv & 7))] =
                    bf16of(ov[w]);
                if (step < 3) {
                    int a = p * 32 + c;
                    float hv = __builtin_bit_cast(float, (unsigned)spb[a] << 16);
                    spb[a] = bf16of(hv + ov[w]);
                }
            }
        }
        __syncthreads();   // outb/spb committed
    }

    // ================= expand: out = ReLU(BN(ew @ outs) + x) ================
    // 16 o-tiles of 16 rows; per tile: wave wid owns j2 = wid*4+q (j2 < 13).
    for (int ot = 0; ot < 16; ++ot) {
        f32x4 acc[4];
        #pragma unroll
        for (int q = 0; q < 4; ++q) acc[q] = (f32x4)0.f;

        #pragma unroll
        for (int kc = 0; kc < 4; ++kc) {
            // A-fragment straight from global ew (L2-hot): 32 B/lane
            const float* wr = ew + (size_t)(ot * 16 + rl) * 128 + kc * 32 + g * 8;
            float4 a0 = *(const float4*)wr;
            float4 a1 = *(const float4*)(wr + 4);
            bf16x8 af = pk8(a0, a1);
            const int gk = kc * 4 + g;
            #pragma unroll
            for (int q = 0; q < 4; ++q) {
                int j2 = wid * 4 + q;
                if (j2 < 13) {
                    int p = j2 * 16 + rl;
                    bf16x8 bfv = *(const bf16x8*)(
                        &outb[p * 128 + ((gk ^ (p & 15)) << 3)]);
                    acc[q] = __builtin_amdgcn_mfma_f32_16x16x32_bf16(
                        af, bfv, acc[q], 0, 0, 0);
                }
            }
        }

        __syncthreads();   // prior eT readers done (store phase / gcn phase)
        #pragma unroll
        for (int q = 0; q < 4; ++q) {
            int j2 = wid * 4 + q;
            if (j2 < 13) {
                #pragma unroll
                for (int r = 0; r < 4; ++r) {
                    int olc = g * 4 + r;
                    int o   = ot * 16 + olc;
                    eT[olc * 212 + j2 * 16 + rl] =
                        fmaf(acc[q][r], escale[o], eshift[o]);
                }
            }
        }
        __syncthreads();

        // cooperative float4 resid + store: 16 o-rows x 200 p
        for (int idx = tid; idx < 800; idx += 256) {
            int ol = idx / 50, p4 = (idx % 50) * 4;
            float4 v = *(const float4*)(&eT[ol * 212 + p4]);
            size_t base = ((size_t)n * 256 + ot * 16 + ol) * 1600
                        + (size_t)tt * 200 + p4;
            float4 rx = *(const float4*)(xres + base);
            v.x = fmaxf(v.x + rx.x, 0.f);
            v.y = fmaxf(v.y + rx.y, 0.f);
            v.z = fmaxf(v.z + rx.z, 0.f);
            v.w = fmaxf(v.w + rx.w, 0.f);
            *(float4*)(outg + base) = v;
        }
    }
}

// ---------------------------------------------------------------------------
extern "C" void kernel_launch(void* const* d_in, const int* in_sizes, int n_in,
                              void* d_out, int out_size, void* d_ws, size_t ws_size,
                              hipStream_t stream)
{
    const float* x   = (const float*)d_in[0];
    const float* A   = (const float*)d_in[1];
    const float* rw  = (const float*)d_in[2];
    const float* rwb = (const float*)d_in[3];
    const float* rg  = (const float*)d_in[4];
    const float* rb  = (const float*)d_in[5];
    const float* rm  = (const float*)d_in[6];
    const float* rv  = (const float*)d_in[7];
    const float* gw  = (const float*)d_in[8];
    const float* gb  = (const float*)d_in[9];
    const float* PA  = (const float*)d_in[10];
    const float* bg  = (const float*)d_in[11];
    const float* bb  = (const float*)d_in[12];
    const float* bm  = (const float*)d_in[13];
    const float* bv  = (const float*)d_in[14];
    const float* ew  = (const float*)d_in[15];
    const float* ewb = (const float*)d_in[16];
    const float* eg  = (const float*)d_in[17];
    const float* eb  = (const float*)d_in[18];
    const float* em  = (const float*)d_in[19];
    const float* ev  = (const float*)d_in[20];

    char* wsb = (char*)d_ws;
    unsigned short* hT  = (unsigned short*)wsb;           // 26,214,400 B
    float*          prm = (float*)(wsb + 26214400);       // 4 KB

    prep_params<<<1, 256, 0, stream>>>(rwb, rg, rb, rm, rv,
                                       ewb, eg, eb, em, ev,
                                       bg, bb, bm, bv, prm);

    // reduct: x -> hT bf16 [n][1600][128]
    gemm_reduct<<<dim3(25, 1, 64), 256, 0, stream>>>(
        x, rw, prm, prm + 128, hT, 256, 128, 1600);

    // fused res2net chain + expand (+x residual) -> d_out
    gcn_expand<<<dim3(8, 64), 256, 0, stream>>>(
        hT, gw, gb, A, PA, prm + 768, prm + 896,
        ew, prm + 256, prm + 512, x, (float*)d_out);
}

// Round 13
// 195.540 us; speedup vs baseline: 28.5114x; 28.0938x over previous
//
#include <hip/hip_runtime.h>
#include <cstdint>
#include <cstddef>

#define EPSV 1e-5f

using f32x4  = __attribute__((ext_vector_type(4))) float;
using bf16x8 = __attribute__((ext_vector_type(8))) short;

// RNE pack of two f32 into two bf16 (lo -> low16, hi -> high16)
static __device__ __forceinline__ unsigned pk2(float lo, float hi) {
    unsigned a = __builtin_bit_cast(unsigned, lo);
    unsigned b = __builtin_bit_cast(unsigned, hi);
    a = (a + 0x7FFFu + ((a >> 16) & 1u)) >> 16;
    b = (b + 0x7FFFu + ((b >> 16) & 1u)) & 0xFFFF0000u;
    return a | b;
}
static __device__ __forceinline__ unsigned short bf16of(float v) {
    return (unsigned short)(pk2(v, 0.f) & 0xFFFFu);
}
static __device__ __forceinline__ float f32of(unsigned short u) {
    return __builtin_bit_cast(float, (unsigned)u << 16);
}
static __device__ __forceinline__ void unpk2(unsigned u, float& lo, float& hi) {
    lo = __builtin_bit_cast(float, u << 16);
    hi = __builtin_bit_cast(float, u & 0xFFFF0000u);
}

// ---------------------------------------------------------------------------
__global__ __launch_bounds__(256) void prep_params(
    const float* __restrict__ rwb, const float* __restrict__ rg,
    const float* __restrict__ rb,  const float* __restrict__ rm,
    const float* __restrict__ rv,
    const float* __restrict__ ewb, const float* __restrict__ eg,
    const float* __restrict__ eb,  const float* __restrict__ em,
    const float* __restrict__ ev,
    const float* __restrict__ bg,  const float* __restrict__ bb,
    const float* __restrict__ bm,  const float* __restrict__ bv,
    float* __restrict__ prm)
{
    int t = threadIdx.x;
    if (t < 128) {
        float sc = rg[t] * rsqrtf(rv[t] + EPSV);
        prm[t]       = sc;
        prm[128 + t] = rb[t] - rm[t] * sc + rwb[t] * sc;
        float bsc = bg[t] * rsqrtf(bv[t] + EPSV);
        prm[768 + t] = bsc;
        prm[896 + t] = bb[t] - bm[t] * bsc;
    }
    {
        float sc = eg[t] * rsqrtf(ev[t] + EPSV);
        prm[256 + t] = sc;
        prm[512 + t] = eb[t] - em[t] * sc + ewb[t] * sc;
    }
}

// ---------------------------------------------------------------------------
// GEMM v2 (round-9/10 verified, unchanged): BK=64, 32 KB LDS, vectorized I/O.
// ---------------------------------------------------------------------------
template<int BMODE, int OUTMODE>
__global__ __launch_bounds__(256) void gemm_v2(
    const void* __restrict__ Bsrc,
    const float* __restrict__ Wt,
    const float* __restrict__ scale,
    const float* __restrict__ shift,
    const float* __restrict__ resid,
    void* __restrict__ OutP,
    int Cin, int O, int P)
{
    const int n    = blockIdx.z;
    const int p0   = blockIdx.x * 64;
    const int o0   = blockIdx.y * 128;
    const int tid  = threadIdx.x;
    const int lane = tid & 63;
    const int wid  = tid >> 6;
    const int wm   = wid >> 1, wn = wid & 1;
    const int rl   = lane & 15;

    __shared__ __align__(16) char smem[32768];
    short* sA = (short*)smem;                       // 16 KB [128][64] swz

    f32x4 acc[4][2];
    #pragma unroll
    for (int i = 0; i < 4; ++i)
        #pragma unroll
        for (int j = 0; j < 2; ++j) acc[i][j] = (f32x4)0.f;

    for (int kc = 0; kc < Cin; kc += 64) {
        if (kc) __syncthreads();

        #pragma unroll
        for (int it = 0; it < 4; ++it) {
            int idx = tid + it * 256;
            int row = idx >> 3, k8 = (idx & 7) << 3;
            const float* wp = Wt + (size_t)(o0 + row) * Cin + kc + k8;
            float4 u = *(const float4*)wp;
            float4 v = *(const float4*)(wp + 4);
            uint4 w = make_uint4(pk2(u.x, u.y), pk2(u.z, u.w),
                                 pk2(v.x, v.y), pk2(v.z, v.w));
            *(uint4*)(&sA[(row << 6) + (k8 ^ ((row & 7) << 3))]) = w;
        }
        if constexpr (BMODE == 0) {
            float* sBf = (float*)(smem + 16384);    // [64 k][64 p] rotated
            #pragma unroll
            for (int it = 0; it < 4; ++it) {
                int idx = tid + it * 256;
                int k = idx >> 4, p4 = (idx & 15) << 2;
                float4 u = *(const float4*)((const float*)Bsrc
                    + (size_t)n * Cin * P + (size_t)(kc + k) * P + p0 + p4);
                *(float4*)(&sBf[(k << 6) + ((p4 + (((k >> 3) & 7) << 3)) & 63)]) = u;
            }
        } else {
            short* sB = (short*)(smem + 16384);     // [64 p][64 k] swz
            #pragma unroll
            for (int it = 0; it < 2; ++it) {
                int idx = tid + it * 256;
                int p = idx >> 3, k8 = (idx & 7) << 3;
                uint4 w = *(const uint4*)((const unsigned short*)Bsrc
                    + ((size_t)n * P + p0 + p) * Cin + kc + k8);
                *(uint4*)(&sB[(p << 6) + (k8 ^ ((p & 7) << 3))]) = w;
            }
        }
        __syncthreads();

        #pragma unroll
        for (int ks = 0; ks < 2; ++ks) {
            const int k0 = ks * 32 + (lane >> 4) * 8;
            bf16x8 af[4], bfr[2];
            #pragma unroll
            for (int i = 0; i < 4; ++i) {
                int row = wm * 64 + i * 16 + rl;
                af[i] = *(const bf16x8*)(&sA[(row << 6) + (k0 ^ ((rl & 7) << 3))]);
            }
            if constexpr (BMODE == 0) {
                const float* sBf = (const float*)(smem + 16384);
                #pragma unroll
                for (int j = 0; j < 2; ++j) {
                    int p = wn * 32 + j * 16 + rl;
                    int base = (p + ((k0 >> 3) << 3)) & 63;
                    float f[8];
                    #pragma unroll
                    for (int q = 0; q < 8; ++q)
                        f[q] = sBf[((k0 + q) << 6) + base];
                    uint4 u = make_uint4(pk2(f[0], f[1]), pk2(f[2], f[3]),
                                         pk2(f[4], f[5]), pk2(f[6], f[7]));
                    bfr[j] = __builtin_bit_cast(bf16x8, u);
                }
            } else {
                const short* sB = (const short*)(smem + 16384);
                #pragma unroll
                for (int j = 0; j < 2; ++j) {
                    int p = wn * 32 + j * 16 + rl;
                    bfr[j] = *(const bf16x8*)(&sB[(p << 6) + (k0 ^ ((rl & 7) << 3))]);
                }
            }
            #pragma unroll
            for (int i = 0; i < 4; ++i)
                #pragma unroll
                for (int j = 0; j < 2; ++j)
                    acc[i][j] = __builtin_amdgcn_mfma_f32_16x16x32_bf16(
                        af[i], bfr[j], acc[i][j], 0, 0, 0);
        }
    }

    if constexpr (OUTMODE == 1) {
        __syncthreads();
        unsigned short* eL = (unsigned short*)smem;   // [64 p][128 o]
        #pragma unroll
        for (int i = 0; i < 4; ++i) {
            #pragma unroll
            for (int r = 0; r < 4; ++r) {
                int ol = wm * 64 + i * 16 + (lane >> 4) * 4 + r;
                int o  = o0 + ol;
                float sc = scale[o], sh = shift[o];
                #pragma unroll
                for (int j = 0; j < 2; ++j) {
                    int p = wn * 32 + j * 16 + rl;
                    float v = fmaxf(fmaf(acc[i][j][r], sc, sh), 0.f);
                    eL[p * 128 + (ol ^ ((p & 15) << 3))] = bf16of(v);
                }
            }
        }
        __syncthreads();
        unsigned short* out = (unsigned short*)OutP;
        #pragma unroll
        for (int it = 0; it < 4; ++it) {
            int idx = tid + it * 256;
            int p = idx >> 4, m = idx & 15;
            uint4 u = *(const uint4*)(&eL[p * 128 + ((m ^ (p & 15)) << 3)]);
            *(uint4*)(out + ((size_t)n * P + p0 + p) * O + (m << 3)) = u;
        }
    } else {
        __syncthreads();
        float* eT = (float*)smem;                     // [128 o][64 p] rotated
        #pragma unroll
        for (int i = 0; i < 4; ++i) {
            #pragma unroll
            for (int r = 0; r < 4; ++r) {
                int ol = wm * 64 + i * 16 + (lane >> 4) * 4 + r;
                int o  = o0 + ol;
                float sc = scale[o], sh = shift[o];
                #pragma unroll
                for (int j = 0; j < 2; ++j) {
                    int p = wn * 32 + j * 16 + rl;
                    eT[(ol << 6) + ((p + ((ol & 7) << 3)) & 63)] =
                        fmaf(acc[i][j][r], sc, sh);
                }
            }
        }
        __syncthreads();
        float* out = (float*)OutP;
        #pragma unroll
        for (int it = 0; it < 8; ++it) {
            int idx = tid + it * 256;
            int ol = idx >> 4, p4 = (idx & 15) << 2;
            float4 v = *(const float4*)(&eT[(ol << 6) + ((p4 + ((ol & 7) << 3)) & 63)]);
            size_t base = ((size_t)n * O + o0 + ol) * P + p0 + p4;
            if (resid) {
                float4 r4 = *(const float4*)(resid + base);
                v.x += r4.x; v.y += r4.y; v.z += r4.z; v.w += r4.w;
            }
            v.x = fmaxf(v.x, 0.f); v.y = fmaxf(v.y, 0.f);
            v.z = fmaxf(v.z, 0.f); v.w = fmaxf(v.w, 0.f);
            *(float4*)(out + base) = v;
        }
    }
}

// ---------------------------------------------------------------------------
// Fused res2net chain (round-10 structure, bf16 LDS state for 3 blocks/CU).
// One block per (n, 200-p tile); 4 steps with barriers between.
// Thread owns (c = tid&31, tl = tid>>5). Conv reads are LDS broadcasts.
// ---------------------------------------------------------------------------
__global__ __launch_bounds__(256) void gcn_fused(
    const unsigned short* __restrict__ hT,   // [64][1600][128] bf16
    unsigned short* __restrict__ outsT,      // [64][1600][128] bf16
    const float* __restrict__ gw,            // [4][96][32]
    const float* __restrict__ gb,            // [4][96]
    const float* __restrict__ Aadj,          // [3][25][25]
    const float* __restrict__ PA,            // [4][3][25][25]
    const float* __restrict__ bsc4,          // [4][32]
    const float* __restrict__ bsh4)          // [4][32]
{
    const int n  = blockIdx.y;
    const int tt = blockIdx.x;
    const int tid = threadIdx.x;
    const int c  = tid & 31;
    const int tl = tid >> 5;

    __shared__ unsigned short spb[200 * 32];    // 12,800 B  bf16 state
    __shared__ float wsg[96 * 33];              // 12,672 B
    __shared__ float Mm[3][25][28];             //  8,400 B
    __shared__ unsigned short outb[200 * 32];   // 12,800 B

    const size_t rowbase = (size_t)n * 1600 + (size_t)tt * 200;

    // ---- init: spb = hT chunk 0 (bf16 copy), weights/Mm step 0 ----
    {
        const unsigned short* hrow = hT + rowbase * 128;
        for (int idx = tid; idx < 800; idx += 256) {
            int p = idx >> 2, c8 = (idx & 3) << 3;
            *(uint4*)(&spb[p * 32 + c8]) =
                *(const uint4*)(hrow + (size_t)p * 128 + c8);
        }
        for (int idx = tid; idx < 96 * 32; idx += 256)
            wsg[(idx >> 5) * 33 + (idx & 31)] = gw[idx];
        for (int idx = tid; idx < 1875; idx += 256) {
            int k = idx / 625, rem = idx % 625;
            Mm[k][rem / 25][rem % 25] = Aadj[idx] + PA[idx];
        }
    }
    __syncthreads();

    for (int step = 0; step < 4; ++step) {
        // ---- conv 32->96 (round-10 form: scalar LDS reads, broadcast) ----
        float g[3][25];
        {
            const float* gbp = gb + step * 96;
            float b0 = gbp[c], b1 = gbp[32 + c], b2 = gbp[64 + c];
            #pragma unroll
            for (int v = 0; v < 25; ++v) { g[0][v] = b0; g[1][v] = b1; g[2][v] = b2; }
        }
        const unsigned short* srow = spb + tl * 25 * 32;
        for (int cin = 0; cin < 32; ++cin) {
            float w0 = wsg[c * 33 + cin];
            float w1 = wsg[(32 + c) * 33 + cin];
            float w2 = wsg[(64 + c) * 33 + cin];
            #pragma unroll
            for (int v = 0; v < 25; ++v) {
                float sv = f32of(srow[v * 32 + cin]);
                g[0][v] = fmaf(w0, sv, g[0][v]);
                g[1][v] = fmaf(w1, sv, g[1][v]);
                g[2][v] = fmaf(w2, sv, g[2][v]);
            }
        }

        // ---- adjacency mix ----
        float out[25];
        #pragma unroll
        for (int w = 0; w < 25; ++w) out[w] = 0.f;
        #pragma unroll
        for (int k = 0; k < 3; ++k)
            #pragma unroll
            for (int v = 0; v < 25; ++v) {
                float gv = g[k][v];
                #pragma unroll
                for (int w = 0; w < 25; ++w)
                    out[w] = fmaf(gv, Mm[k][v][w], out[w]);
            }

        // ---- BN + ReLU ----
        {
            float sc = bsc4[step * 32 + c], sh = bsh4[step * 32 + c];
            #pragma unroll
            for (int w = 0; w < 25; ++w)
                out[w] = fmaxf(fmaf(out[w], sc, sh), 0.f);
        }

        __syncthreads();   // conv/mix reads of spb, wsg, Mm complete

        // ---- commit: spb = out (state), outb = out (bf16) ----
        #pragma unroll
        for (int w = 0; w < 25; ++w) {
            unsigned short b = bf16of(out[w]);
            spb[(tl * 25 + w) * 32 + c]  = b;
            outb[(tl * 25 + w) * 32 + c] = b;
        }
        __syncthreads();   // spb/outb committed

        // ---- store outb -> outsT chunk `step` (coalesced uint4) ----
        {
            unsigned short* orow = outsT + rowbase * 128 + step * 32;
            for (int idx = tid; idx < 800; idx += 256) {
                int p = idx >> 2, c8 = (idx & 3) << 3;
                uint4 u = *(const uint4*)(&outb[p * 32 + c8]);
                *(uint4*)(orow + (size_t)p * 128 + c8) = u;
            }
        }

        if (step < 3) {
            // ---- spb += h chunk step+1 (uint4 RMW); stage next weights ----
            const unsigned short* hrow = hT + rowbase * 128 + (step + 1) * 32;
            for (int idx = tid; idx < 800; idx += 256) {
                int p = idx >> 2, c8 = (idx & 3) << 3;
                uint4 u = *(const uint4*)(hrow + (size_t)p * 128 + c8);
                uint4 s = *(const uint4*)(&spb[p * 32 + c8]);
                float hf[8], sf[8];
                unpk2(u.x, hf[0], hf[1]); unpk2(u.y, hf[2], hf[3]);
                unpk2(u.z, hf[4], hf[5]); unpk2(u.w, hf[6], hf[7]);
                unpk2(s.x, sf[0], sf[1]); unpk2(s.y, sf[2], sf[3]);
                unpk2(s.z, sf[4], sf[5]); unpk2(s.w, sf[6], sf[7]);
                uint4 r = make_uint4(pk2(sf[0] + hf[0], sf[1] + hf[1]),
                                     pk2(sf[2] + hf[2], sf[3] + hf[3]),
                                     pk2(sf[4] + hf[4], sf[5] + hf[5]),
                                     pk2(sf[6] + hf[6], sf[7] + hf[7]));
                *(uint4*)(&spb[p * 32 + c8]) = r;
            }
            const float* gwp = gw + (step + 1) * 96 * 32;
            for (int idx = tid; idx < 96 * 32; idx += 256)
                wsg[(idx >> 5) * 33 + (idx & 31)] = gwp[idx];
            const float* pap = PA + (step + 1) * 1875;
            for (int idx = tid; idx < 1875; idx += 256) {
                int k = idx / 625, rem = idx % 625;
                Mm[k][rem / 25][rem % 25] = Aadj[idx] + pap[idx];
            }
            __syncthreads();   // spb/wsg/Mm ready for next conv
        }
    }
}

// ---------------------------------------------------------------------------
extern "C" void kernel_launch(void* const* d_in, const int* in_sizes, int n_in,
                              void* d_out, int out_size, void* d_ws, size_t ws_size,
                              hipStream_t stream)
{
    const float* x   = (const float*)d_in[0];
    const float* A   = (const float*)d_in[1];
    const float* rw  = (const float*)d_in[2];
    const float* rwb = (const float*)d_in[3];
    const float* rg  = (const float*)d_in[4];
    const float* rb  = (const float*)d_in[5];
    const float* rm  = (const float*)d_in[6];
    const float* rv  = (const float*)d_in[7];
    const float* gw  = (const float*)d_in[8];
    const float* gb  = (const float*)d_in[9];
    const float* PA  = (const float*)d_in[10];
    const float* bg  = (const float*)d_in[11];
    const float* bb  = (const float*)d_in[12];
    const float* bm  = (const float*)d_in[13];
    const float* bv  = (const float*)d_in[14];
    const float* ew  = (const float*)d_in[15];
    const float* ewb = (const float*)d_in[16];
    const float* eg  = (const float*)d_in[17];
    const float* eb  = (const float*)d_in[18];
    const float* em  = (const float*)d_in[19];
    const float* ev  = (const float*)d_in[20];

    char* wsb = (char*)d_ws;
    unsigned short* hT    = (unsigned short*)wsb;               // 26,214,400 B
    unsigned short* outsT = (unsigned short*)(wsb + 26214400);  // 26,214,400 B
    float*          prm   = (float*)(wsb + 52428800);           // 4 KB

    prep_params<<<1, 256, 0, stream>>>(rwb, rg, rb, rm, rv,
                                       ewb, eg, eb, em, ev,
                                       bg, bb, bm, bv, prm);

    // reduct: x f32 [n][256][1600] -> hT bf16 [n][1600][128]
    gemm_v2<0, 1><<<dim3(25, 1, 64), 256, 0, stream>>>(
        x, rw, prm, prm + 128, nullptr, hT, 256, 128, 1600);

    // fused res2net chain (4 steps, one launch)
    gcn_fused<<<dim3(8, 64), 256, 0, stream>>>(
        hT, outsT, gw, gb, A, PA, prm + 768, prm + 896);

    // expand: outsT bf16 -> d_out f32 [n][256][1600] (+x residual)
    gemm_v2<1, 0><<<dim3(25, 2, 64), 256, 0, stream>>>(
        outsT, ew, prm + 256, prm + 512, x, d_out, 128, 256, 1600);
}

// Round 14
// 194.607 us; speedup vs baseline: 28.6481x; 1.0048x over previous
//
#include <hip/hip_runtime.h>
#include <cstdint>
#include <cstddef>

#define EPSV 1e-5f

using f32x4  = __attribute__((ext_vector_type(4))) float;
using bf16x8 = __attribute__((ext_vector_type(8))) short;

// RNE pack of two f32 into two bf16 (lo -> low16, hi -> high16)
static __device__ __forceinline__ unsigned pk2(float lo, float hi) {
    unsigned a = __builtin_bit_cast(unsigned, lo);
    unsigned b = __builtin_bit_cast(unsigned, hi);
    a = (a + 0x7FFFu + ((a >> 16) & 1u)) >> 16;
    b = (b + 0x7FFFu + ((b >> 16) & 1u)) & 0xFFFF0000u;
    return a | b;
}
static __device__ __forceinline__ unsigned short bf16of(float v) {
    return (unsigned short)(pk2(v, 0.f) & 0xFFFFu);
}
static __device__ __forceinline__ float f32of(unsigned short u) {
    return __builtin_bit_cast(float, (unsigned)u << 16);
}
static __device__ __forceinline__ void unpk2(unsigned u, float& lo, float& hi) {
    lo = __builtin_bit_cast(float, u << 16);
    hi = __builtin_bit_cast(float, u & 0xFFFF0000u);
}

// ---------------------------------------------------------------------------
__global__ __launch_bounds__(256) void prep_params(
    const float* __restrict__ rwb, const float* __restrict__ rg,
    const float* __restrict__ rb,  const float* __restrict__ rm,
    const float* __restrict__ rv,
    const float* __restrict__ ewb, const float* __restrict__ eg,
    const float* __restrict__ eb,  const float* __restrict__ em,
    const float* __restrict__ ev,
    const float* __restrict__ bg,  const float* __restrict__ bb,
    const float* __restrict__ bm,  const float* __restrict__ bv,
    float* __restrict__ prm)
{
    int t = threadIdx.x;
    if (t < 128) {
        float sc = rg[t] * rsqrtf(rv[t] + EPSV);
        prm[t]       = sc;
        prm[128 + t] = rb[t] - rm[t] * sc + rwb[t] * sc;
        float bsc = bg[t] * rsqrtf(bv[t] + EPSV);
        prm[768 + t] = bsc;
        prm[896 + t] = bb[t] - bm[t] * bsc;
    }
    {
        float sc = eg[t] * rsqrtf(ev[t] + EPSV);
        prm[256 + t] = sc;
        prm[512 + t] = eb[t] - em[t] * sc + ewb[t] * sc;
    }
}

// ---------------------------------------------------------------------------
// GEMM v3: software-pipelined double-buffered LDS (round-5 verified loop) +
// round-9 verified vectorized staging / fragments / epilogues. BK=32.
// Tile 128(o) x 64(p), 4 waves (2x2). One barrier per K-step; global loads
// for step t+1 are issued BEFORE the barrier and drained after compute(t).
// sA rows: LDR=40 shorts (80 B, 16B-aligned, 2-way banks max).
// BMODE 0: B f32 [NB][Cin][P] staged into rotated [32k][64p] f32 tiles.
// BMODE 1: B bf16 [NB][P][Cin] staged into [64p][40] bf16 rows.
// OUTMODE 1: bf16 [NB][P][O] transposed epilogue. OUTMODE 0: f32 [NB][O][P]
// LDS-restaged float4 epilogue with resid+ReLU.
// ---------------------------------------------------------------------------
#define LDR 40

template<int BMODE, int OUTMODE>
__global__ __launch_bounds__(256) void gemm_v3(
    const void* __restrict__ Bsrc,
    const float* __restrict__ Wt,
    const float* __restrict__ scale,
    const float* __restrict__ shift,
    const float* __restrict__ resid,
    void* __restrict__ OutP,
    int Cin, int O, int P)
{
    const int n    = blockIdx.z;
    const int p0   = blockIdx.x * 64;
    const int o0   = blockIdx.y * 128;
    const int tid  = threadIdx.x;
    const int lane = tid & 63;
    const int wid  = tid >> 6;
    const int wm   = wid >> 1, wn = wid & 1;
    const int rl   = lane & 15;

    // smem: [sA dbuf 2x10240][B dbuf 2x(8192 f32 | 5120 bf16)]
    constexpr int SMEM = (BMODE == 0)
        ? (20480 + 16384)                 // 36,864 B
        : ((20480 + 10240) < 32768 ? 32768 : (20480 + 10240));  // eT needs 32 KB
    __shared__ __align__(16) char smem[SMEM];
    short* sA = (short*)smem;             // [2][128*LDR]

    // A staging map: 2 threads/row
    const int ao = tid >> 1;
    const int ak = (tid & 1) * 16;

    f32x4 acc[4][2];
    #pragma unroll
    for (int i = 0; i < 4; ++i)
        #pragma unroll
        for (int j = 0; j < 2; ++j) acc[i][j] = (f32x4)0.f;

    float4 ra[4];
    float4 rb0, rb1;     // BMODE 0
    uint4  rbu;          // BMODE 1

    const int nt = Cin >> 5;

    auto load_regs = [&](int t) {
        const int kc = t << 5;
        const float* wrow = Wt + (size_t)(o0 + ao) * Cin + kc + ak;
        #pragma unroll
        for (int i = 0; i < 4; ++i)
            ra[i] = *(const float4*)(wrow + i * 4);
        if constexpr (BMODE == 0) {
            const float* bp = (const float*)Bsrc + (size_t)n * Cin * P;
            int s0 = tid, s1 = tid + 256;            // slots: k = s>>4, p4 = (s&15)<<2
            rb0 = *(const float4*)(bp + (size_t)(kc + (s0 >> 4)) * P + p0 + ((s0 & 15) << 2));
            rb1 = *(const float4*)(bp + (size_t)(kc + (s1 >> 4)) * P + p0 + ((s1 & 15) << 2));
        } else {
            const unsigned short* bp = (const unsigned short*)Bsrc;
            int p = tid >> 2, k8 = (tid & 3) << 3;
            rbu = *(const uint4*)(bp + ((size_t)n * P + p0 + p) * Cin + kc + k8);
        }
    };

    auto write_lds = [&](int buf) {
        short* a = sA + buf * (128 * LDR);
        uint4 w0 = make_uint4(pk2(ra[0].x, ra[0].y), pk2(ra[0].z, ra[0].w),
                              pk2(ra[1].x, ra[1].y), pk2(ra[1].z, ra[1].w));
        uint4 w1 = make_uint4(pk2(ra[2].x, ra[2].y), pk2(ra[2].z, ra[2].w),
                              pk2(ra[3].x, ra[3].y), pk2(ra[3].z, ra[3].w));
        *(uint4*)(a + ao * LDR + ak)     = w0;
        *(uint4*)(a + ao * LDR + ak + 8) = w1;
        if constexpr (BMODE == 0) {
            float* sBf = (float*)(smem + 20480) + buf * 2048;  // [32k][64p] rot
            int s0 = tid, s1 = tid + 256;
            int k0r = s0 >> 4, p40 = (s0 & 15) << 2;
            int k1r = s1 >> 4, p41 = (s1 & 15) << 2;
            *(float4*)(&sBf[(k0r << 6) + ((p40 + (((k0r >> 3) & 7) << 3)) & 63)]) = rb0;
            *(float4*)(&sBf[(k1r << 6) + ((p41 + (((k1r >> 3) & 7) << 3)) & 63)]) = rb1;
        } else {
            short* sB = (short*)(smem + 20480) + buf * (64 * LDR);
            int p = tid >> 2, k8 = (tid & 3) << 3;
            *(uint4*)(sB + p * LDR + k8) = rbu;
        }
    };

    auto compute = [&](int buf) {
        const short* a = sA + buf * (128 * LDR);
        const int k0 = (lane >> 4) * 8;
        bf16x8 af[4], bfr[2];
        #pragma unroll
        for (int i = 0; i < 4; ++i)
            af[i] = *(const bf16x8*)(a + (wm * 64 + i * 16 + rl) * LDR + k0);
        if constexpr (BMODE == 0) {
            const float* sBf = (const float*)(smem + 20480) + buf * 2048;
            #pragma unroll
            for (int j = 0; j < 2; ++j) {
                int p = wn * 32 + j * 16 + rl;
                int base = (p + ((k0 >> 3) << 3)) & 63;
                float f[8];
                #pragma unroll
                for (int q = 0; q < 8; ++q)
                    f[q] = sBf[((k0 + q) << 6) + base];
                uint4 u = make_uint4(pk2(f[0], f[1]), pk2(f[2], f[3]),
                                     pk2(f[4], f[5]), pk2(f[6], f[7]));
                bfr[j] = __builtin_bit_cast(bf16x8, u);
            }
        } else {
            const short* sB = (const short*)(smem + 20480) + buf * (64 * LDR);
            #pragma unroll
            for (int j = 0; j < 2; ++j)
                bfr[j] = *(const bf16x8*)(sB + (wn * 32 + j * 16 + rl) * LDR + k0);
        }
        #pragma unroll
        for (int i = 0; i < 4; ++i)
            #pragma unroll
            for (int j = 0; j < 2; ++j)
                acc[i][j] = __builtin_amdgcn_mfma_f32_16x16x32_bf16(
                    af[i], bfr[j], acc[i][j], 0, 0, 0);
    };

    // round-5 verified pipeline: 1 barrier per K-step, loads overlap compute
    load_regs(0);
    write_lds(0);
    for (int t = 0; t < nt; ++t) {
        if (t + 1 < nt) load_regs(t + 1);
        __syncthreads();
        compute(t & 1);
        if (t + 1 < nt) write_lds((t + 1) & 1);
    }

    if constexpr (OUTMODE == 1) {
        __syncthreads();
        unsigned short* eL = (unsigned short*)smem;   // [64 p][128 o]
        #pragma unroll
        for (int i = 0; i < 4; ++i) {
            #pragma unroll
            for (int r = 0; r < 4; ++r) {
                int ol = wm * 64 + i * 16 + (lane >> 4) * 4 + r;
                int o  = o0 + ol;
                float sc = scale[o], sh = shift[o];
                #pragma unroll
                for (int j = 0; j < 2; ++j) {
                    int p = wn * 32 + j * 16 + rl;
                    float v = fmaxf(fmaf(acc[i][j][r], sc, sh), 0.f);
                    eL[p * 128 + (ol ^ ((p & 15) << 3))] = bf16of(v);
                }
            }
        }
        __syncthreads();
        unsigned short* out = (unsigned short*)OutP;
        #pragma unroll
        for (int it = 0; it < 4; ++it) {
            int idx = tid + it * 256;
            int p = idx >> 4, m = idx & 15;
            uint4 u = *(const uint4*)(&eL[p * 128 + ((m ^ (p & 15)) << 3)]);
            *(uint4*)(out + ((size_t)n * P + p0 + p) * O + (m << 3)) = u;
        }
    } else {
        __syncthreads();
        float* eT = (float*)smem;                     // [128 o][64 p] rotated
        #pragma unroll
        for (int i = 0; i < 4; ++i) {
            #pragma unroll
            for (int r = 0; r < 4; ++r) {
                int ol = wm * 64 + i * 16 + (lane >> 4) * 4 + r;
                int o  = o0 + ol;
                float sc = scale[o], sh = shift[o];
                #pragma unroll
                for (int j = 0; j < 2; ++j) {
                    int p = wn * 32 + j * 16 + rl;
                    eT[(ol << 6) + ((p + ((ol & 7) << 3)) & 63)] =
                        fmaf(acc[i][j][r], sc, sh);
                }
            }
        }
        __syncthreads();
        float* out = (float*)OutP;
        #pragma unroll
        for (int it = 0; it < 8; ++it) {
            int idx = tid + it * 256;
            int ol = idx >> 4, p4 = (idx & 15) << 2;
            float4 v = *(const float4*)(&eT[(ol << 6) + ((p4 + ((ol & 7) << 3)) & 63)]);
            size_t base = ((size_t)n * O + o0 + ol) * P + p0 + p4;
            if (resid) {
                float4 r4 = *(const float4*)(resid + base);
                v.x += r4.x; v.y += r4.y; v.z += r4.z; v.w += r4.w;
            }
            v.x = fmaxf(v.x, 0.f); v.y = fmaxf(v.y, 0.f);
            v.z = fmaxf(v.z, 0.f); v.w = fmaxf(v.w, 0.f);
            *(float4*)(out + base) = v;
        }
    }
}

// ---------------------------------------------------------------------------
// Fused res2net chain (round-13 verified, unchanged).
// ---------------------------------------------------------------------------
__global__ __launch_bounds__(256) void gcn_fused(
    const unsigned short* __restrict__ hT,
    unsigned short* __restrict__ outsT,
    const float* __restrict__ gw,
    const float* __restrict__ gb,
    const float* __restrict__ Aadj,
    const float* __restrict__ PA,
    const float* __restrict__ bsc4,
    const float* __restrict__ bsh4)
{
    const int n  = blockIdx.y;
    const int tt = blockIdx.x;
    const int tid = threadIdx.x;
    const int c  = tid & 31;
    const int tl = tid >> 5;

    __shared__ unsigned short spb[200 * 32];
    __shared__ float wsg[96 * 33];
    __shared__ float Mm[3][25][28];
    __shared__ unsigned short outb[200 * 32];

    const size_t rowbase = (size_t)n * 1600 + (size_t)tt * 200;

    {
        const unsigned short* hrow = hT + rowbase * 128;
        for (int idx = tid; idx < 800; idx += 256) {
            int p = idx >> 2, c8 = (idx & 3) << 3;
            *(uint4*)(&spb[p * 32 + c8]) =
                *(const uint4*)(hrow + (size_t)p * 128 + c8);
        }
        for (int idx = tid; idx < 96 * 32; idx += 256)
            wsg[(idx >> 5) * 33 + (idx & 31)] = gw[idx];
        for (int idx = tid; idx < 1875; idx += 256) {
            int k = idx / 625, rem = idx % 625;
            Mm[k][rem / 25][rem % 25] = Aadj[idx] + PA[idx];
        }
    }
    __syncthreads();

    for (int step = 0; step < 4; ++step) {
        float g[3][25];
        {
            const float* gbp = gb + step * 96;
            float b0 = gbp[c], b1 = gbp[32 + c], b2 = gbp[64 + c];
            #pragma unroll
            for (int v = 0; v < 25; ++v) { g[0][v] = b0; g[1][v] = b1; g[2][v] = b2; }
        }
        const unsigned short* srow = spb + tl * 25 * 32;
        for (int cin = 0; cin < 32; ++cin) {
            float w0 = wsg[c * 33 + cin];
            float w1 = wsg[(32 + c) * 33 + cin];
            float w2 = wsg[(64 + c) * 33 + cin];
            #pragma unroll
            for (int v = 0; v < 25; ++v) {
                float sv = f32of(srow[v * 32 + cin]);
                g[0][v] = fmaf(w0, sv, g[0][v]);
                g[1][v] = fmaf(w1, sv, g[1][v]);
                g[2][v] = fmaf(w2, sv, g[2][v]);
            }
        }

        float out[25];
        #pragma unroll
        for (int w = 0; w < 25; ++w) out[w] = 0.f;
        #pragma unroll
        for (int k = 0; k < 3; ++k)
            #pragma unroll
            for (int v = 0; v < 25; ++v) {
                float gv = g[k][v];
                #pragma unroll
                for (int w = 0; w < 25; ++w)
                    out[w] = fmaf(gv, Mm[k][v][w], out[w]);
            }

        {
            float sc = bsc4[step * 32 + c], sh = bsh4[step * 32 + c];
            #pragma unroll
            for (int w = 0; w < 25; ++w)
                out[w] = fmaxf(fmaf(out[w], sc, sh), 0.f);
        }

        __syncthreads();

        #pragma unroll
        for (int w = 0; w < 25; ++w) {
            unsigned short b = bf16of(out[w]);
            spb[(tl * 25 + w) * 32 + c]  = b;
            outb[(tl * 25 + w) * 32 + c] = b;
        }
        __syncthreads();

        {
            unsigned short* orow = outsT + rowbase * 128 + step * 32;
            for (int idx = tid; idx < 800; idx += 256) {
                int p = idx >> 2, c8 = (idx & 3) << 3;
                uint4 u = *(const uint4*)(&outb[p * 32 + c8]);
                *(uint4*)(orow + (size_t)p * 128 + c8) = u;
            }
        }

        if (step < 3) {
            const unsigned short* hrow = hT + rowbase * 128 + (step + 1) * 32;
            for (int idx = tid; idx < 800; idx += 256) {
                int p = idx >> 2, c8 = (idx & 3) << 3;
                uint4 u = *(const uint4*)(hrow + (size_t)p * 128 + c8);
                uint4 s = *(const uint4*)(&spb[p * 32 + c8]);
                float hf[8], sf[8];
                unpk2(u.x, hf[0], hf[1]); unpk2(u.y, hf[2], hf[3]);
                unpk2(u.z, hf[4], hf[5]); unpk2(u.w, hf[6], hf[7]);
                unpk2(s.x, sf[0], sf[1]); unpk2(s.y, sf[2], sf[3]);
                unpk2(s.z, sf[4], sf[5]); unpk2(s.w, sf[6], sf[7]);
                uint4 r = make_uint4(pk2(sf[0] + hf[0], sf[1] + hf[1]),
                                     pk2(sf[2] + hf[2], sf[3] + hf[3]),
                                     pk2(sf[4] + hf[4], sf[5] + hf[5]),
                                     pk2(sf[6] + hf[6], sf[7] + hf[7]));
                *(uint4*)(&spb[p * 32 + c8]) = r;
            }
            const float* gwp = gw + (step + 1) * 96 * 32;
            for (int idx = tid; idx < 96 * 32; idx += 256)
                wsg[(idx >> 5) * 33 + (idx & 31)] = gwp[idx];
            const float* pap = PA + (step + 1) * 1875;
            for (int idx = tid; idx < 1875; idx += 256) {
                int k = idx / 625, rem = idx % 625;
                Mm[k][rem / 25][rem % 25] = Aadj[idx] + pap[idx];
            }
            __syncthreads();
        }
    }
}

// ---------------------------------------------------------------------------
extern "C" void kernel_launch(void* const* d_in, const int* in_sizes, int n_in,
                              void* d_out, int out_size, void* d_ws, size_t ws_size,
                              hipStream_t stream)
{
    const float* x   = (const float*)d_in[0];
    const float* A   = (const float*)d_in[1];
    const float* rw  = (const float*)d_in[2];
    const float* rwb = (const float*)d_in[3];
    const float* rg  = (const float*)d_in[4];
    const float* rb  = (const float*)d_in[5];
    const float* rm  = (const float*)d_in[6];
    const float* rv  = (const float*)d_in[7];
    const float* gw  = (const float*)d_in[8];
    const float* gb  = (const float*)d_in[9];
    const float* PA  = (const float*)d_in[10];
    const float* bg  = (const float*)d_in[11];
    const float* bb  = (const float*)d_in[12];
    const float* bm  = (const float*)d_in[13];
    const float* bv  = (const float*)d_in[14];
    const float* ew  = (const float*)d_in[15];
    const float* ewb = (const float*)d_in[16];
    const float* eg  = (const float*)d_in[17];
    const float* eb  = (const float*)d_in[18];
    const float* em  = (const float*)d_in[19];
    const float* ev  = (const float*)d_in[20];

    char* wsb = (char*)d_ws;
    unsigned short* hT    = (unsigned short*)wsb;               // 26,214,400 B
    unsigned short* outsT = (unsigned short*)(wsb + 26214400);  // 26,214,400 B
    float*          prm   = (float*)(wsb + 52428800);           // 4 KB

    prep_params<<<1, 256, 0, stream>>>(rwb, rg, rb, rm, rv,
                                       ewb, eg, eb, em, ev,
                                       bg, bb, bm, bv, prm);

    // reduct: x f32 [n][256][1600] -> hT bf16 [n][1600][128]
    gemm_v3<0, 1><<<dim3(25, 1, 64), 256, 0, stream>>>(
        x, rw, prm, prm + 128, nullptr, hT, 256, 128, 1600);

    // fused res2net chain (4 steps, one launch)
    gcn_fused<<<dim3(8, 64), 256, 0, stream>>>(
        hT, outsT, gw, gb, A, PA, prm + 768, prm + 896);

    // expand: outsT bf16 -> d_out f32 [n][256][1600] (+x residual)
    gemm_v3<1, 0><<<dim3(25, 2, 64), 256, 0, stream>>>(
        outsT, ew, prm + 256, prm + 512, x, d_out, 128, 256, 1600);
}